// Round 9
// baseline (694.213 us; speedup 1.0000x reference)
//
#include <hip/hip_runtime.h>
#include <hip/hip_bf16.h>
#include <stdint.h>
#include <stddef.h>

// ---------------------------------------------------------------------------
// Connectivity3D: PointNet (6->64->128->256, BN folded, max-pool) ->
// object_embedding -> 2x GCN -> edge MLP -> tanh -> [512,16,16].
//
// Algebraic collapse: dense intra-object edges => deg=16 for every node =>
// GCN output = (per-object mean of xw) + b, identical for all 16 parts =>
// ONE edge score per object; only fsum[obj] = sum_parts feat is needed.
//
// R14 = 256-thread / 256-register redesign. R13 closed the model: LDS read
// pipe 94% busy (672 b128/CU-iter x 12cyc + 3.5K conflict cyc = 12.7K of
// 13.5K cyc); L3's redundancy-8 (each of 8 waves re-reads full 32KB h2) is
// 76% of reads and irreducible at 128 regs (af3[4][4] spills - R12).
// This round: 256-thr blocks (4 waves), __launch_bounds__(256,2) -> 256
// VGPR budget (documented: 2nd arg = min waves/EU). 512 blocks -> 2
// blocks/CU, 1 wave/block/SIMD -> block B's wave covers block A's barrier
// stalls. Same chunk=128 skeleton + LDS layout:
//   L1 = 2ct x 4pt (af1[2]);  L2 = 2ct x 8pt (af2[2][2]);
//   L3 = 8ct x 4pt (af3[8][4]=128 VGPR, redundancy 8 -> 2),
//   cross-wave pt-half max combine via pmax[2][256] (no new barriers).
// Reads/block-iter 336 -> 144. Statics 188, peak ~232 <= 256.
// FIRST CHECK: WRITE_SIZE ~7.7e3 (no spill). If it ballooned -> 128-reg
// cap is structural -> revert to R10/R13 plateau as final.
// (Resubmitted unchanged after R8 GPUAcquisitionTimeout — never measured.)
// ---------------------------------------------------------------------------

typedef short bf16x8 __attribute__((ext_vector_type(8)));
typedef short bf16x4 __attribute__((ext_vector_type(4)));
typedef float f32x4  __attribute__((ext_vector_type(4)));

// workspace byte offsets (all 16B aligned)
#define WT1_OFF   0u        // bf16 [64][32]  (W1*g1)^T, col6 = bias, cols7-31 = 0
#define WT2_OFF   4096u     // bf16 [128][64] (W2*g2)^T
#define WT3_OFF   20480u    // bf16 [256][128](W3*g3)^T
#define B1F_OFF   86016u    // f32 [64] (unused; layout keep)
#define B2F_OFF   86272u    // f32 [128]
#define B3F_OFF   86784u    // f32 [256]

__device__ __forceinline__ unsigned short f2bf(float f) {
  union { float f; unsigned u; } v; v.f = f;
  unsigned r = v.u + 0x7fffu + ((v.u >> 16) & 1u);   // round-to-nearest-even
  return (unsigned short)(r >> 16);
}

__device__ __forceinline__ unsigned pack2bf(float a, float b) {
  __hip_bfloat162 h = __float22bfloat162_rn(make_float2(a, b));
  union { __hip_bfloat162 h; unsigned u; } u; u.h = h;
  return u.u;
}

__device__ __forceinline__ bf16x4 pack_relu4(f32x4 d) {
  __hip_bfloat162 lo = __float22bfloat162_rn(make_float2(fmaxf(d.x, 0.f), fmaxf(d.y, 0.f)));
  __hip_bfloat162 hi = __float22bfloat162_rn(make_float2(fmaxf(d.z, 0.f), fmaxf(d.w, 0.f)));
  union { bf16x4 v; __hip_bfloat162 h[2]; } u;
  u.h[0] = lo; u.h[1] = hi;
  return u.v;
}

// ---------------------------------------------------------------------------
__global__ void prep_kernel(
    const float* __restrict__ W1, const float* __restrict__ b1,
    const float* __restrict__ g1, const float* __restrict__ bt1,
    const float* __restrict__ W2, const float* __restrict__ b2,
    const float* __restrict__ g2, const float* __restrict__ bt2,
    const float* __restrict__ W3, const float* __restrict__ b3,
    const float* __restrict__ g3, const float* __restrict__ bt3,
    unsigned char* __restrict__ ws)
{
  unsigned short* wt1 = (unsigned short*)(ws + WT1_OFF);
  unsigned short* wt2 = (unsigned short*)(ws + WT2_OFF);
  unsigned short* wt3 = (unsigned short*)(ws + WT3_OFF);
  float* b1f  = (float*)(ws + B1F_OFF);
  float* b2f  = (float*)(ws + B2F_OFF);
  float* b3f  = (float*)(ws + B3F_OFF);

  int i = blockIdx.x * 256 + threadIdx.x;
  if (i < 2048) { int o = i >> 5, c = i & 31;                 // wt1[o][c]
    float v = (c < 6) ? W1[c*64 + o] * g1[o]
            : (c == 6 ? (b1[o]*g1[o] + bt1[o]) : 0.f);        // bias-in-col6
    wt1[i] = f2bf(v); return; }
  i -= 2048;
  if (i < 8192) { int o = i >> 6, c = i & 63;                 // wt2[o][c]
    wt2[i] = f2bf(W2[c*128 + o] * g2[o]); return; }
  i -= 8192;
  if (i < 32768) { int o = i >> 7, c = i & 127;               // wt3[o][c]
    wt3[i] = f2bf(W3[c*256 + o] * g3[o]); return; }
  i -= 32768;
  if (i < 64)  { b1f[i] = b1[i]*g1[i] + bt1[i]; return; }
  i -= 64;
  if (i < 128) { b2f[i] = b2[i]*g2[i] + bt2[i]; return; }
  i -= 128;
  if (i < 256) { b3f[i] = b3[i]*g3[i] + bt3[i]; }
}

// ---------------------------------------------------------------------------
// One block per object: 512 blocks x 256 thr (4 waves), 8192 pts, chunk=128,
// 64 iterations, 2 barriers/iter. Then in-block MLP epilogue.
// LDS (short idx): x[128][40] @0, h1[128][72] @5120, h2[128][136] @14336,
//                  fsacc f32[256] @31744, pmax f32[2][256] @32256.
#define LDSX  0
#define LDSH1 5120
#define LDSH2 14336
#define LDSFS 31744
#define LDSPM 32256

__global__ __launch_bounds__(256, 2)
void pointnet_fused_kernel(
    const float* __restrict__ pcls, const unsigned char* __restrict__ ws,
    const float* __restrict__ We,  const float* __restrict__ be,
    const float* __restrict__ Wg1, const float* __restrict__ bg1,
    const float* __restrict__ Wg2, const float* __restrict__ bg2,
    const float* __restrict__ Wc1, const float* __restrict__ bc1,
    const float* __restrict__ Wc2, const float* __restrict__ bc2,
    const float* __restrict__ Wc3, const float* __restrict__ bc3,
    float* __restrict__ out)
{
  __shared__ __align__(16) unsigned short lds[33280];   // 66560 B -> 2 blocks/CU

  const unsigned short* wt1 = (const unsigned short*)(ws + WT1_OFF);
  const unsigned short* wt2 = (const unsigned short*)(ws + WT2_OFF);
  const unsigned short* wt3 = (const unsigned short*)(ws + WT3_OFF);
  const float* b2f = (const float*)(ws + B2F_OFF);
  const float* b3f = (const float*)(ws + B3F_OFF);

  const int tid  = threadIdx.x;     // 0..255
  const int w    = tid >> 6;        // wave 0..3
  const int lane = tid & 63;
  const int l15  = lane & 15;
  const int q    = lane >> 4;       // quad 0..3
  const int obj  = blockIdx.x;

  const int c1g = w & 1;            // L1 ct-pair base c1g*2 (of 4 ct)
  const int p1g = w >> 1;           // L1 pt-quad base p1g*4 (of 8 pt-tiles)
  const int ct2 = w * 2;            // L2 ct pair: 2w, 2w+1 (of 8); all 8 pt
  const int cg3 = w & 1;            // L3 ct-octet base cg3*8 (of 16 ct)
  const int pg  = w >> 1;           // L3 pt-quad base pg*4 (of 8 pt-tiles)

  // Weight A-fragments, register-resident. A[m=l15][k=q*8+j].
  bf16x8 af1[2], af2[2][2], af3[8][4];
#pragma unroll
  for (int ct = 0; ct < 2; ++ct)
    af1[ct] = *(const bf16x8*)(wt1 + ((c1g*2 + ct)*16 + l15)*32 + q*8);
#pragma unroll
  for (int ct = 0; ct < 2; ++ct)
#pragma unroll
    for (int kf = 0; kf < 2; ++kf)
      af2[ct][kf] = *(const bf16x8*)(wt2 + ((ct2 + ct)*16 + l15)*64 + kf*32 + q*8);
#pragma unroll
  for (int ct = 0; ct < 8; ++ct)
#pragma unroll
    for (int kf = 0; kf < 4; ++kf)
      af3[ct][kf] = *(const bf16x8*)(wt3 + ((cg3*8 + ct)*16 + l15)*128 + kf*32 + q*8);

  f32x4 bs2[2];
#pragma unroll
  for (int ct = 0; ct < 2; ++ct)
    bs2[ct] = *(const f32x4*)(b2f + (ct2 + ct)*16 + q*4);

  // point staging: 768 floats/chunk with 256 threads.
  // t<128: row=t, loads 2x float2 (elems 6t..6t+3) -> packed dwords 0,1
  // t>=128: row=t-128, loads float2 (elems 6r+4..6r+5) -> packed dword 2
  const int srow  = tid & 127;
  const int shalf = tid >> 7;
  unsigned* ldsu = (unsigned*)lds;

  // init x: zeros; col6 = 1.0 (bias channel); fsacc = 0
  for (int i = tid; i < 5120; i += 256) ldsu[i] = 0;   // x = 5120 dwords
  ((float*)&lds[LDSFS])[tid] = 0.f;
  __syncthreads();
  if (tid < 128) lds[LDSX + tid*40 + 6] = 0x3F80;   // bf16 1.0 (disjoint slot)

  const float* pbase = pcls + (size_t)obj * 49152;   // 8192 pts * 6
  {
    if (shalf == 0) {
      const float2 a0 = *(const float2*)(pbase + 6*srow);
      const float2 a1 = *(const float2*)(pbase + 6*srow + 2);
      ldsu[srow*20 + 0] = pack2bf(a0.x, a0.y);
      ldsu[srow*20 + 1] = pack2bf(a1.x, a1.y);
    } else {
      const float2 a2 = *(const float2*)(pbase + 6*srow + 4);
      ldsu[srow*20 + 2] = pack2bf(a2.x, a2.y);
    }
  }
  __syncthreads();

  f32x4 macc[8];
#pragma unroll
  for (int ct = 0; ct < 8; ++ct)
    macc[ct] = (f32x4){-3e38f, -3e38f, -3e38f, -3e38f};

  // ---- prologue: L1(0): x(0) -> h1  (2ct x 4pt per wave)
#pragma unroll
  for (int i = 0; i < 4; ++i) {
    const int pt = p1g*4 + i;
    bf16x8 b = *(const bf16x8*)(&lds[LDSX + (pt*16 + l15)*40 + q*8]);
#pragma unroll
    for (int ct = 0; ct < 2; ++ct) {
      f32x4 d = {0.f, 0.f, 0.f, 0.f};
      d = __builtin_amdgcn_mfma_f32_16x16x32_bf16(af1[ct], b, d, 0, 0, 0);
      *(bf16x4*)(&lds[LDSH1 + (pt*16 + l15)*72 + (c1g*2 + ct)*16 + q*4]) = pack_relu4(d);
    }
  }
  __syncthreads();                   // h1(0) ready; x(0) reads done

  for (int cg = 0; cg < 64; ++cg) {
    const int havenext = (cg < 63);

    // ==== Phase A: L2(cg): h1 -> h2; stage x(cg+1); fold prev boundary ===
    float2 a0, a1;
    if (havenext) {
      if (shalf == 0) {
        a0 = *(const float2*)(pbase + (cg + 1)*768 + 6*srow);
        a1 = *(const float2*)(pbase + (cg + 1)*768 + 6*srow + 2);
      } else {
        a0 = *(const float2*)(pbase + (cg + 1)*768 + 6*srow + 4);
      }
    }
    if ((cg & 3) == 0 && cg > 0) {    // fold boundary (cg-1) pmax (all 256 thr)
      float* pm = (float*)&lds[LDSPM];
      float* fsacc = (float*)&lds[LDSFS];
      fsacc[tid] += fmaxf(pm[tid], pm[256 + tid]);
    }
#pragma unroll
    for (int pt = 0; pt < 8; ++pt) {
      bf16x8 b0  = *(const bf16x8*)(&lds[LDSH1 + (pt*16 + l15)*72 + q*8]);
      bf16x8 b1v = *(const bf16x8*)(&lds[LDSH1 + (pt*16 + l15)*72 + 32 + q*8]);
#pragma unroll
      for (int ct = 0; ct < 2; ++ct) {
        f32x4 d = bs2[ct];
        d = __builtin_amdgcn_mfma_f32_16x16x32_bf16(af2[ct][0], b0,  d, 0, 0, 0);
        d = __builtin_amdgcn_mfma_f32_16x16x32_bf16(af2[ct][1], b1v, d, 0, 0, 0);
        *(bf16x4*)(&lds[LDSH2 + (pt*16 + l15)*136 + (ct2 + ct)*16 + q*4]) = pack_relu4(d);
      }
    }
    // stage x(cg+1): x reads for L1(cg) finished in B(cg-1), barrier since
    if (havenext) {
      if (shalf == 0) {
        ldsu[srow*20 + 0] = pack2bf(a0.x, a0.y);
        ldsu[srow*20 + 1] = pack2bf(a1.x, a1.y);
      } else {
        ldsu[srow*20 + 2] = pack2bf(a0.x, a0.y);
      }
    }
    __syncthreads();                 // h2 ready; x(cg+1) visible; h1 reads done

    // ==== Phase B: L1(cg+1): x -> h1 ; L3(cg): h2 -> macc ===============
    if (havenext) {
#pragma unroll
      for (int i = 0; i < 4; ++i) {
        const int pt = p1g*4 + i;
        bf16x8 b = *(const bf16x8*)(&lds[LDSX + (pt*16 + l15)*40 + q*8]);
#pragma unroll
        for (int ct = 0; ct < 2; ++ct) {
          f32x4 d = {0.f, 0.f, 0.f, 0.f};
          d = __builtin_amdgcn_mfma_f32_16x16x32_bf16(af1[ct], b, d, 0, 0, 0);
          *(bf16x4*)(&lds[LDSH1 + (pt*16 + l15)*72 + (c1g*2 + ct)*16 + q*4]) = pack_relu4(d);
        }
      }
    }
    // L3: wave's 4 pt-tiles x 8 ch-tiles; 16 reads, 128 MFMAs
#pragma unroll
    for (int pt = 0; pt < 4; ++pt) {
      const int ptt = pg*4 + pt;
      bf16x8 b[4];
#pragma unroll
      for (int kf = 0; kf < 4; ++kf)
        b[kf] = *(const bf16x8*)(&lds[LDSH2 + (ptt*16 + l15)*136 + kf*32 + q*8]);
#pragma unroll
      for (int ct = 0; ct < 8; ++ct) {
        f32x4 d = {0.f, 0.f, 0.f, 0.f};
#pragma unroll
        for (int kf = 0; kf < 4; ++kf)
          d = __builtin_amdgcn_mfma_f32_16x16x32_bf16(af3[ct][kf], b[kf], d, 0, 0, 0);
#pragma unroll
        for (int r = 0; r < 4; ++r)
          macc[ct][r] = fmaxf(macc[ct][r], d[r]);
      }
    }
    // part boundary (512 pts = 4 chunks): reduce max over 16 pt-lanes and
    // stage wave's pt-half partial into pmax for cross-wave combine
    if ((cg & 3) == 3) {
      float* pm = (float*)&lds[LDSPM];
#pragma unroll
      for (int ct = 0; ct < 8; ++ct) {
        f32x4 v = macc[ct];
#pragma unroll
        for (int r = 0; r < 4; ++r) {
          float x = v[r];
          x = fmaxf(x, __shfl_xor(x, 1));
          x = fmaxf(x, __shfl_xor(x, 2));
          x = fmaxf(x, __shfl_xor(x, 4));
          x = fmaxf(x, __shfl_xor(x, 8));
          v[r] = x;
        }
        if (l15 == 0)
          *(f32x4*)(pm + pg*256 + (cg3*8 + ct)*16 + q*4) = v;
        macc[ct] = (f32x4){-3e38f, -3e38f, -3e38f, -3e38f};
      }
    }
    __syncthreads();                 // h1(cg+1)/pmax ready; h2 reads done
  }

  // final boundary combine + bias3 fold (all 256 threads)
  {
    float* pm = (float*)&lds[LDSPM];
    float* fsacc = (float*)&lds[LDSFS];
    fsacc[tid] += fmaxf(pm[tid], pm[256 + tid]);
    fsacc[tid] += 16.f * b3f[tid];
  }
  __syncthreads();

  // =========================================================================
  // In-block per-object MLP epilogue, 256 threads (each owns one channel).
  // LDS float scratch (x region reused): bA[256] @0, bB[256] @256,
  // redv[4] @512; fs @ LDSFS.
  // Chain: fs -(We,+16be)-> bA -(Wg1,/16+bg1,relu)-> bB -(Wg2,+bg2)-> bA
  //        -(Wc1 src+dst,+bc1,relu)-> bB -(Wc2,+bc2,relu)-> bA -.Wc3-> tanh
  // =========================================================================
  float* fls  = (float*)&lds[0];
  float* fs   = (float*)&lds[LDSFS];
  float* bA   = fls;
  float* bB   = fls + 256;
  float* redv = fls + 512;
  float a;

  // p1: bA = fs@We + 16*be
  a = 0.f;
#pragma unroll 8
  for (int c = 0; c < 256; ++c) a += fs[c] * We[c*256 + tid];
  bA[tid] = a + 16.f * be[tid];
  __syncthreads();

  // p2: bB = relu(bA@Wg1 / 16 + bg1)
  a = 0.f;
#pragma unroll 8
  for (int c = 0; c < 256; ++c) a += bA[c] * Wg1[c*256 + tid];
  bB[tid] = fmaxf(a * 0.0625f + bg1[tid], 0.f);
  __syncthreads();

  // p3: bA = bB@Wg2 + bg2
  a = 0.f;
#pragma unroll 8
  for (int c = 0; c < 256; ++c) a += bB[c] * Wg2[c*256 + tid];
  bA[tid] = a + bg2[tid];
  __syncthreads();

  // p4: bB = relu(bA@(Wc1_src + Wc1_dst) + bc1)
  a = 0.f;
#pragma unroll 8
  for (int c = 0; c < 256; ++c) {
    const float xv = bA[c];
    a += xv * Wc1[c*256 + tid];
    a += xv * Wc1[(c + 256)*256 + tid];
  }
  bB[tid] = fmaxf(a + bc1[tid], 0.f);
  __syncthreads();

  // p5: bA = relu(bB@Wc2 + bc2)
  a = 0.f;
#pragma unroll 8
  for (int c = 0; c < 256; ++c) a += bB[c] * Wc2[c*256 + tid];
  bA[tid] = fmaxf(a + bc2[tid], 0.f);
  __syncthreads();

  // p6: scalar = bA . Wc3; tanh; broadcast into 16x16 (zero diagonal)
  float prod = bA[tid] * Wc3[tid];
#pragma unroll
  for (int off = 1; off < 64; off <<= 1) prod += __shfl_xor(prod, off);
  if (lane == 0) redv[w] = prod;
  __syncthreads();
  if (tid == 0) redv[0] = tanhf(redv[0] + redv[1] + redv[2] + redv[3] + bc3[0]);
  __syncthreads();
  const float cv = redv[0];
  out[obj*256 + tid] = ((tid >> 4) == (tid & 15)) ? 0.f : cv;
}

// ---------------------------------------------------------------------------
extern "C" void kernel_launch(void* const* d_in, const int* in_sizes, int n_in,
                              void* d_out, int out_size, void* d_ws, size_t ws_size,
                              hipStream_t stream) {
  const float* pcls = (const float*)d_in[0];
  const float* W1 = (const float*)d_in[1];  const float* b1 = (const float*)d_in[2];
  const float* g1 = (const float*)d_in[3];  const float* bt1 = (const float*)d_in[4];
  const float* W2 = (const float*)d_in[5];  const float* b2 = (const float*)d_in[6];
  const float* g2 = (const float*)d_in[7];  const float* bt2 = (const float*)d_in[8];
  const float* W3 = (const float*)d_in[9];  const float* b3 = (const float*)d_in[10];
  const float* g3 = (const float*)d_in[11]; const float* bt3 = (const float*)d_in[12];
  const float* We = (const float*)d_in[13]; const float* be = (const float*)d_in[14];
  const float* Wg1 = (const float*)d_in[15]; const float* bg1 = (const float*)d_in[16];
  const float* Wg2 = (const float*)d_in[17]; const float* bg2 = (const float*)d_in[18];
  const float* Wc1 = (const float*)d_in[19]; const float* bc1 = (const float*)d_in[20];
  const float* Wc2 = (const float*)d_in[21]; const float* bc2 = (const float*)d_in[22];
  const float* Wc3 = (const float*)d_in[23]; const float* bc3 = (const float*)d_in[24];
  unsigned char* ws = (unsigned char*)d_ws;
  float* out = (float*)d_out;

  prep_kernel<<<170, 256, 0, stream>>>(W1, b1, g1, bt1, W2, b2, g2, bt2,
                                       W3, b3, g3, bt3, ws);
  pointnet_fused_kernel<<<512, 256, 0, stream>>>(
      pcls, ws, We, be, Wg1, bg1, Wg2, bg2, Wc1, bc1, Wc2, bc2, Wc3, bc3, out);
}

// Round 14
// 480.887 us; speedup vs baseline: 1.4436x; 1.4436x over previous
//
#include <hip/hip_runtime.h>
#include <hip/hip_bf16.h>
#include <stdint.h>
#include <stddef.h>

// ---------------------------------------------------------------------------
// Connectivity3D: PointNet (6->64->128->256, BN folded, max-pool) ->
// object_embedding -> 2x GCN -> edge MLP -> tanh -> [512,16,16].
//
// Algebraic collapse: dense intra-object edges => deg=16 for every node =>
// GCN output = (per-object mean of xw) + b, identical for all 16 parts =>
// ONE edge score per object; only fsum[obj] = sum_parts feat is needed.
//
// R15 = chunk=64 TLP redesign. Evidence: 128-VGPR cap is structural (3
// spill disasters: R11/R12/R14); R10's 44 reads/wave/128pts is at the
// register-constrained floor (~42); neither LDS (71%) nor MFMA (48%) pipe
// saturated -> ~30% is unhidden dependency/barrier serialization; R10's
// waves_per_eu(4,4) PINNED occupancy at 4 waves/EU (16/CU).
// Fix: halve the chunk -> LDS/block = exactly 32 KB -> 4 blocks/CU, up to
// 32 waves/CU; attribute relaxed to waves_per_eu(4) (min-only: 128-reg cap
// kept, occupancy ceiling removed). Same dataflow, same traffic per point:
//   L1 = 2ct x 1pt (1 read);  L2 = 2ct x 2pt (4);  L3 = 2ct x 4pt (16).
// Each wave owns its 2 L3-channels over the WHOLE chunk -> pmax cross-wave
// combine eliminated (direct fsacc accumulate, race-free).
// FIRST CHECK: WRITE_SIZE ~7.7e3 (no spill), Occupancy ~60-75%.
// (Resubmitted unchanged after four GPUAcquisitionTimeouts — never measured.)
// ---------------------------------------------------------------------------

typedef short bf16x8 __attribute__((ext_vector_type(8)));
typedef short bf16x4 __attribute__((ext_vector_type(4)));
typedef float f32x4  __attribute__((ext_vector_type(4)));

// workspace byte offsets (all 16B aligned)
#define WT1_OFF   0u        // bf16 [64][32]  (W1*g1)^T, col6 = bias, cols7-31 = 0
#define WT2_OFF   4096u     // bf16 [128][64] (W2*g2)^T
#define WT3_OFF   20480u    // bf16 [256][128](W3*g3)^T
#define B1F_OFF   86016u    // f32 [64] (unused; layout keep)
#define B2F_OFF   86272u    // f32 [128]
#define B3F_OFF   86784u    // f32 [256]

__device__ __forceinline__ unsigned short f2bf(float f) {
  union { float f; unsigned u; } v; v.f = f;
  unsigned r = v.u + 0x7fffu + ((v.u >> 16) & 1u);   // round-to-nearest-even
  return (unsigned short)(r >> 16);
}

__device__ __forceinline__ unsigned pack2bf(float a, float b) {
  __hip_bfloat162 h = __float22bfloat162_rn(make_float2(a, b));
  union { __hip_bfloat162 h; unsigned u; } u; u.h = h;
  return u.u;
}

__device__ __forceinline__ bf16x4 pack_relu4(f32x4 d) {
  __hip_bfloat162 lo = __float22bfloat162_rn(make_float2(fmaxf(d.x, 0.f), fmaxf(d.y, 0.f)));
  __hip_bfloat162 hi = __float22bfloat162_rn(make_float2(fmaxf(d.z, 0.f), fmaxf(d.w, 0.f)));
  union { bf16x4 v; __hip_bfloat162 h[2]; } u;
  u.h[0] = lo; u.h[1] = hi;
  return u.v;
}

// ---------------------------------------------------------------------------
__global__ void prep_kernel(
    const float* __restrict__ W1, const float* __restrict__ b1,
    const float* __restrict__ g1, const float* __restrict__ bt1,
    const float* __restrict__ W2, const float* __restrict__ b2,
    const float* __restrict__ g2, const float* __restrict__ bt2,
    const float* __restrict__ W3, const float* __restrict__ b3,
    const float* __restrict__ g3, const float* __restrict__ bt3,
    unsigned char* __restrict__ ws)
{
  unsigned short* wt1 = (unsigned short*)(ws + WT1_OFF);
  unsigned short* wt2 = (unsigned short*)(ws + WT2_OFF);
  unsigned short* wt3 = (unsigned short*)(ws + WT3_OFF);
  float* b1f  = (float*)(ws + B1F_OFF);
  float* b2f  = (float*)(ws + B2F_OFF);
  float* b3f  = (float*)(ws + B3F_OFF);

  int i = blockIdx.x * 256 + threadIdx.x;
  if (i < 2048) { int o = i >> 5, c = i & 31;                 // wt1[o][c]
    float v = (c < 6) ? W1[c*64 + o] * g1[o]
            : (c == 6 ? (b1[o]*g1[o] + bt1[o]) : 0.f);        // bias-in-col6
    wt1[i] = f2bf(v); return; }
  i -= 2048;
  if (i < 8192) { int o = i >> 6, c = i & 63;                 // wt2[o][c]
    wt2[i] = f2bf(W2[c*128 + o] * g2[o]); return; }
  i -= 8192;
  if (i < 32768) { int o = i >> 7, c = i & 127;               // wt3[o][c]
    wt3[i] = f2bf(W3[c*256 + o] * g3[o]); return; }
  i -= 32768;
  if (i < 64)  { b1f[i] = b1[i]*g1[i] + bt1[i]; return; }
  i -= 64;
  if (i < 128) { b2f[i] = b2[i]*g2[i] + bt2[i]; return; }
  i -= 128;
  if (i < 256) { b3f[i] = b3[i]*g3[i] + bt3[i]; }
}

// ---------------------------------------------------------------------------
// One block per object: 512 blocks x 512 thr (8 waves), 8192 pts, chunk=64,
// 128 iterations, 2 barriers/iter. Then in-block MLP epilogue.
// LDS (short idx): x[64][40] @0, h1[64][72] @2560, h2[64][136] @7168,
//                  fsacc f32[256] @15872.  Total 16384 sh = 32768 B
//                  -> 4 blocks/CU (128 KB of 160 KB).
#define LDSX  0
#define LDSH1 2560
#define LDSH2 7168
#define LDSFS 15872

__global__ __launch_bounds__(512)
__attribute__((amdgpu_waves_per_eu(4)))
void pointnet_fused_kernel(
    const float* __restrict__ pcls, const unsigned char* __restrict__ ws,
    const float* __restrict__ We,  const float* __restrict__ be,
    const float* __restrict__ Wg1, const float* __restrict__ bg1,
    const float* __restrict__ Wg2, const float* __restrict__ bg2,
    const float* __restrict__ Wc1, const float* __restrict__ bc1,
    const float* __restrict__ Wc2, const float* __restrict__ bc2,
    const float* __restrict__ Wc3, const float* __restrict__ bc3,
    float* __restrict__ out)
{
  __shared__ __align__(16) unsigned short lds[16384];   // 32768 B exactly

  const unsigned short* wt1 = (const unsigned short*)(ws + WT1_OFF);
  const unsigned short* wt2 = (const unsigned short*)(ws + WT2_OFF);
  const unsigned short* wt3 = (const unsigned short*)(ws + WT3_OFF);
  const float* b2f = (const float*)(ws + B2F_OFF);
  const float* b3f = (const float*)(ws + B3F_OFF);

  const int tid  = threadIdx.x;
  const int w    = tid >> 6;        // wave 0..7
  const int lane = tid & 63;
  const int l15  = lane & 15;
  const int q    = lane >> 4;       // quad 0..3
  const int obj  = blockIdx.x;

  const int c1g = w & 1;            // L1 ct-pair base c1g*2 (of 4 ct)
  const int p1g = w >> 1;           // L1 pt-tile p1g (of 4)
  const int ct2 = (w & 3) * 2;      // L2 ct pair (of 8 ct); pt-pair pb2
  const int pb2 = (w >> 2) * 2;     // L2 pt-tiles pb2, pb2+1 (of 4)
  // L3: wave owns global ch-tiles 2w, 2w+1 (of 16); ALL 4 pt-tiles.

  // Weight A-fragments, register-resident. A[m=l15][k=q*8+j].
  bf16x8 af1[2], af2[2][2], af3[2][4];
#pragma unroll
  for (int ct = 0; ct < 2; ++ct)
    af1[ct] = *(const bf16x8*)(wt1 + ((c1g*2 + ct)*16 + l15)*32 + q*8);
#pragma unroll
  for (int ct = 0; ct < 2; ++ct)
#pragma unroll
    for (int kf = 0; kf < 2; ++kf)
      af2[ct][kf] = *(const bf16x8*)(wt2 + ((ct2 + ct)*16 + l15)*64 + kf*32 + q*8);
#pragma unroll
  for (int nt = 0; nt < 2; ++nt)
#pragma unroll
    for (int kf = 0; kf < 4; ++kf)
      af3[nt][kf] = *(const bf16x8*)(wt3 + ((2*w + nt)*16 + l15)*128 + kf*32 + q*8);

  f32x4 bs2[2];
#pragma unroll
  for (int ct = 0; ct < 2; ++ct)
    bs2[ct] = *(const f32x4*)(b2f + (ct2 + ct)*16 + q*4);

  // point staging: 384 floats/chunk; 192 threads each load a float2 and
  // write ONE packed dword (2 bf16). sp = row (0..63), sc = ch-pair (0..2).
  const int sv = tid < 192;
  const int sp = tid / 3;
  const int sc = tid % 3;
  unsigned* ldsu = (unsigned*)lds;

  // init x: zeros, col6 = 1.0 (bias channel); fsacc = 0
  for (int i = tid; i < 1280; i += 512) ldsu[i] = 0;    // x = 1280 dwords
  if (tid < 256) ((float*)&lds[LDSFS])[tid] = 0.f;
  __syncthreads();
  if (tid < 64) lds[LDSX + tid*40 + 6] = 0x3F80;        // bf16 1.0

  const float* pbase = pcls + (size_t)obj * 49152;      // 8192 pts * 6
  if (sv) {
    const float2 pv = *(const float2*)(pbase + 2*tid);
    ldsu[sp*20 + sc] = pack2bf(pv.x, pv.y);
  }
  __syncthreads();

  f32x4 macc[2];
#pragma unroll
  for (int nt = 0; nt < 2; ++nt)
    macc[nt] = (f32x4){-3e38f, -3e38f, -3e38f, -3e38f};

  // ---- prologue: L1(0): x(0) -> h1  (2ct x 1pt per wave)
  {
    bf16x8 b = *(const bf16x8*)(&lds[LDSX + (p1g*16 + l15)*40 + q*8]);
#pragma unroll
    for (int ct = 0; ct < 2; ++ct) {
      f32x4 d = {0.f, 0.f, 0.f, 0.f};
      d = __builtin_amdgcn_mfma_f32_16x16x32_bf16(af1[ct], b, d, 0, 0, 0);
      *(bf16x4*)(&lds[LDSH1 + (p1g*16 + l15)*72 + (c1g*2 + ct)*16 + q*4]) = pack_relu4(d);
    }
  }
  __syncthreads();                   // h1(0) ready; x(0) reads done

  for (int cg = 0; cg < 128; ++cg) {
    const int havenext = (cg < 127);

    // ==== Phase A: L2(cg): h1 -> h2; stage x(cg+1) =======================
    float2 pv;
    if (havenext && sv)
      pv = *(const float2*)(pbase + (cg + 1)*384 + 2*tid);
#pragma unroll
    for (int pt = 0; pt < 2; ++pt) {
      const int ptt = pb2 + pt;
      bf16x8 b0  = *(const bf16x8*)(&lds[LDSH1 + (ptt*16 + l15)*72 + q*8]);
      bf16x8 b1v = *(const bf16x8*)(&lds[LDSH1 + (ptt*16 + l15)*72 + 32 + q*8]);
#pragma unroll
      for (int ct = 0; ct < 2; ++ct) {
        f32x4 d = bs2[ct];
        d = __builtin_amdgcn_mfma_f32_16x16x32_bf16(af2[ct][0], b0,  d, 0, 0, 0);
        d = __builtin_amdgcn_mfma_f32_16x16x32_bf16(af2[ct][1], b1v, d, 0, 0, 0);
        *(bf16x4*)(&lds[LDSH2 + (ptt*16 + l15)*136 + (ct2 + ct)*16 + q*4]) = pack_relu4(d);
      }
    }
    // stage x(cg+1): x reads for L1(cg) finished in B(cg-1), barrier since
    if (havenext && sv)
      ldsu[sp*20 + sc] = pack2bf(pv.x, pv.y);
    __syncthreads();                 // h2 ready; x(cg+1) visible; h1 reads done

    // ==== Phase B: L1(cg+1): x -> h1 ; L3(cg): h2 -> macc ===============
    if (havenext) {
      bf16x8 b = *(const bf16x8*)(&lds[LDSX + (p1g*16 + l15)*40 + q*8]);
#pragma unroll
      for (int ct = 0; ct < 2; ++ct) {
        f32x4 d = {0.f, 0.f, 0.f, 0.f};
        d = __builtin_amdgcn_mfma_f32_16x16x32_bf16(af1[ct], b, d, 0, 0, 0);
        *(bf16x4*)(&lds[LDSH1 + (p1g*16 + l15)*72 + (c1g*2 + ct)*16 + q*4]) = pack_relu4(d);
      }
    }
    // L3: wave's 2 ch-tiles over all 4 pt-tiles; 16 reads, 32 MFMAs
#pragma unroll
    for (int pt = 0; pt < 4; ++pt) {
      bf16x8 b[4];
#pragma unroll
      for (int kf = 0; kf < 4; ++kf)
        b[kf] = *(const bf16x8*)(&lds[LDSH2 + (pt*16 + l15)*136 + kf*32 + q*8]);
#pragma unroll
      for (int nt = 0; nt < 2; ++nt) {
        f32x4 d = {0.f, 0.f, 0.f, 0.f};
#pragma unroll
        for (int kf = 0; kf < 4; ++kf)
          d = __builtin_amdgcn_mfma_f32_16x16x32_bf16(af3[nt][kf], b[kf], d, 0, 0, 0);
#pragma unroll
        for (int r = 0; r < 4; ++r)
          macc[nt][r] = fmaxf(macc[nt][r], d[r]);
      }
    }
    // part boundary (512 pts = 8 chunks): reduce max over the 16 pt-lanes,
    // accumulate into LDS fsacc (unique writer per channel -> race-free)
    if ((cg & 7) == 7) {
      float* fsacc = (float*)&lds[LDSFS];
#pragma unroll
      for (int nt = 0; nt < 2; ++nt) {
#pragma unroll
        for (int r = 0; r < 4; ++r) {
          float v = macc[nt][r];
          v = fmaxf(v, __shfl_xor(v, 1));
          v = fmaxf(v, __shfl_xor(v, 2));
          v = fmaxf(v, __shfl_xor(v, 4));
          v = fmaxf(v, __shfl_xor(v, 8));
          if (l15 == 0) fsacc[(2*w + nt)*16 + q*4 + r] += v;
        }
        macc[nt] = (f32x4){-3e38f, -3e38f, -3e38f, -3e38f};
      }
    }
    __syncthreads();                 // h1(cg+1)/fsacc ready; h2 reads done
  }

  // =========================================================================
  // In-block per-object MLP epilogue. LDS float scratch (x region reused):
  // bA[256] @0, bB[256] @256, part[2][256] @512, red[8] @1024; fs @ LDSFS.
  // Chain: fs -(We,+16be)-> bA -(Wg1,/16+bg1,relu)-> bB -(Wg2,+bg2)-> bA
  //        -(Wc1 src+dst,+bc1,relu)-> bB -(Wc2,+bc2,relu)-> bA -.Wc3-> tanh
  // =========================================================================
  float* fls  = (float*)&lds[0];
  float* fs   = (float*)&lds[LDSFS];
  float* bA   = fls;
  float* bB   = fls + 256;
  float* part = fls + 512;
  float* redv = fls + 1024;

  if (tid < 256) fs[tid] += 16.f * b3f[tid];   // bias3 folded post-max
  __syncthreads();

  const int tt = tid & 255, hh = tid >> 8;
  const int cb = hh * 128;
  float a;

  // p1: bA = fs@We + 16*be
  a = 0.f;
#pragma unroll 8
  for (int c = 0; c < 128; ++c) a += fs[cb + c] * We[(cb + c)*256 + tt];
  part[hh*256 + tt] = a;
  __syncthreads();
  if (hh == 0) bA[tt] = part[tt] + part[256 + tt] + 16.f * be[tt];
  __syncthreads();

  // p2: bB = relu(bA@Wg1 / 16 + bg1)
  a = 0.f;
#pragma unroll 8
  for (int c = 0; c < 128; ++c) a += bA[cb + c] * Wg1[(cb + c)*256 + tt];
  part[hh*256 + tt] = a;
  __syncthreads();
  if (hh == 0) bB[tt] = fmaxf((part[tt] + part[256 + tt]) * 0.0625f + bg1[tt], 0.f);
  __syncthreads();

  // p3: bA = bB@Wg2 + bg2
  a = 0.f;
#pragma unroll 8
  for (int c = 0; c < 128; ++c) a += bB[cb + c] * Wg2[(cb + c)*256 + tt];
  part[hh*256 + tt] = a;
  __syncthreads();
  if (hh == 0) bA[tt] = part[tt] + part[256 + tt] + bg2[tt];
  __syncthreads();

  // p4: bB = relu(bA@(Wc1_src + Wc1_dst) + bc1)
  a = 0.f;
#pragma unroll 8
  for (int c = 0; c < 128; ++c) {
    const float xv = bA[cb + c];
    a += xv * Wc1[(cb + c)*256 + tt];
    a += xv * Wc1[(cb + c + 256)*256 + tt];
  }
  part[hh*256 + tt] = a;
  __syncthreads();
  if (hh == 0) bB[tt] = fmaxf(part[tt] + part[256 + tt] + bc1[tt], 0.f);
  __syncthreads();

  // p5: bA = relu(bB@Wc2 + bc2)
  a = 0.f;
#pragma unroll 8
  for (int c = 0; c < 128; ++c) a += bB[cb + c] * Wc2[(cb + c)*256 + tt];
  part[hh*256 + tt] = a;
  __syncthreads();
  if (hh == 0) bA[tt] = fmaxf(part[tt] + part[256 + tt] + bc2[tt], 0.f);
  __syncthreads();

  // p6: scalar = bA . Wc3; tanh; broadcast into 16x16 (zero diagonal)
  float prod = (hh == 0) ? bA[tt] * Wc3[tt] : 0.f;
#pragma unroll
  for (int off = 1; off < 64; off <<= 1) prod += __shfl_xor(prod, off);
  if (lane == 0) redv[w] = prod;
  __syncthreads();
  if (tid == 0) redv[0] = tanhf(redv[0] + redv[1] + redv[2] + redv[3] + bc3[0]);
  __syncthreads();
  const float cv = redv[0];
  if (hh == 0)
    out[obj*256 + tt] = ((tt >> 4) == (tt & 15)) ? 0.f : cv;
}

// ---------------------------------------------------------------------------
extern "C" void kernel_launch(void* const* d_in, const int* in_sizes, int n_in,
                              void* d_out, int out_size, void* d_ws, size_t ws_size,
                              hipStream_t stream) {
  const float* pcls = (const float*)d_in[0];
  const float* W1 = (const float*)d_in[1];  const float* b1 = (const float*)d_in[2];
  const float* g1 = (const float*)d_in[3];  const float* bt1 = (const float*)d_in[4];
  const float* W2 = (const float*)d_in[5];  const float* b2 = (const float*)d_in[6];
  const float* g2 = (const float*)d_in[7];  const float* bt2 = (const float*)d_in[8];
  const float* W3 = (const float*)d_in[9];  const float* b3 = (const float*)d_in[10];
  const float* g3 = (const float*)d_in[11]; const float* bt3 = (const float*)d_in[12];
  const float* We = (const float*)d_in[13]; const float* be = (const float*)d_in[14];
  const float* Wg1 = (const float*)d_in[15]; const float* bg1 = (const float*)d_in[16];
  const float* Wg2 = (const float*)d_in[17]; const float* bg2 = (const float*)d_in[18];
  const float* Wc1 = (const float*)d_in[19]; const float* bc1 = (const float*)d_in[20];
  const float* Wc2 = (const float*)d_in[21]; const float* bc2 = (const float*)d_in[22];
  const float* Wc3 = (const float*)d_in[23]; const float* bc3 = (const float*)d_in[24];
  unsigned char* ws = (unsigned char*)d_ws;
  float* out = (float*)d_out;

  prep_kernel<<<170, 256, 0, stream>>>(W1, b1, g1, bt1, W2, b2, g2, bt2,
                                       W3, b3, g3, bt3, ws);
  pointnet_fused_kernel<<<512, 512, 0, stream>>>(
      pcls, ws, We, be, Wg1, bg1, Wg2, bg2, Wc1, bc1, Wc2, bc2, Wc3, bc3, out);
}